// Round 11
// baseline (523.254 us; speedup 1.0000x reference)
//
#include <hip/hip_runtime.h>

#define NN 100000
#define EE 1600000
#define CC 128
#define NP 100032   // padded to 64-row tiles (1563 * 64)
#define NBK 782     // dst buckets of 128 nodes (782*128 = 100096 >= NN)
#define BCAP 2304   // bucket capacity: E/NBK=2046 expected, +5.6 sigma slack
#define NBS 782     // 128-row MFMA tiles (782*128 = 100096 >= NP)

typedef _Float16 f16;
typedef __attribute__((ext_vector_type(2))) f16 f16x2;
typedef __attribute__((ext_vector_type(8))) f16 f16x8;
typedef __attribute__((ext_vector_type(4))) float f32x4;

#define MFMA16(a, b, c) __builtin_amdgcn_mfma_f32_16x16x32_f16(a, b, c, 0, 0, 0)

// acc += lo/hi f16 of v, via v_fma_mix_f32 (fold cvt+add; x1.0 fma is exact).
// Pure-VALU asm (no mem ops) -> safe w.r.t. scheduling.
#define ACC_MIX(A0, A1, V)                                                    \
  asm("v_fma_mix_f32 %0, %2, 1.0, %0 op_sel:[0,0,0] op_sel_hi:[1,0,0]\n\t"    \
      "v_fma_mix_f32 %1, %2, 1.0, %1 op_sel:[1,0,0] op_sel_hi:[1,0,0]"        \
      : "+v"(A0), "+v"(A1)                                                    \
      : "v"(V))

// LEDGER (R1-R10): flat [row][128ch] + wave-per-node 16-deep gather is the
// aggregate optimum. R10 FOUND: xa/xb were 8B-misaligned through R9 -> every
// 256B gathered row straddled 3 cache lines; 256B-aligning the layout cut
// FETCH 257->178 MB, dur 75.6->58.2 us. Aggregate is now VALU-bound
// (VALUBusy ~80%). Failed challengers: 16ch slabs (R2), LDS atomics (R3,
// 50x), quad/node (R4), degree-sort atomics (R5), oct+partials (R6), NT
// hints (R7), sub-hist CSR (R7), agg+sage fusion (R8, occ 70->33%).
// This round: fma_mix accumulate + 8/8 tail split (VALU cut ~35%).
// LAYOUT INVARIANT: keep all ws buffers 256B-aligned (off+NN+4 does this).

// ---- phase 1: partition edges into dst-buckets; rank saved from 1st pass ----
__global__ __launch_bounds__(1024) void k_part(const int* __restrict__ src,
                                               const int* __restrict__ dst,
                                               int* __restrict__ bcur,
                                               unsigned* __restrict__ bedge) {
  __shared__ int hist[NBK];
  __shared__ int base[NBK];
  const int t = threadIdx.x;
  for (int i = t; i < NBK; i += 1024) hist[i] = 0;
  __syncthreads();
  const int4* src4 = (const int4*)src;
  const int4* dst4 = (const int4*)dst;
  int4 s[4], d[4];
  int rk[16];
  bool val[4];
#pragma unroll
  for (int w = 0; w < 4; w++) {
    int i4 = blockIdx.x * 4096 + w * 1024 + t;
    val[w] = (i4 < EE / 4);
    if (val[w]) {
      s[w] = src4[i4];
      d[w] = dst4[i4];
      rk[w * 4 + 0] = atomicAdd(&hist[d[w].x >> 7], 1);
      rk[w * 4 + 1] = atomicAdd(&hist[d[w].y >> 7], 1);
      rk[w * 4 + 2] = atomicAdd(&hist[d[w].z >> 7], 1);
      rk[w * 4 + 3] = atomicAdd(&hist[d[w].w >> 7], 1);
    }
  }
  __syncthreads();
  for (int i = t; i < NBK; i += 1024) {
    int c = hist[i];
    base[i] = c ? atomicAdd(&bcur[i], c) : 0;
  }
  __syncthreads();
#pragma unroll
  for (int w = 0; w < 4; w++) {
    if (val[w]) {
      int ss[4] = {s[w].x, s[w].y, s[w].z, s[w].w};
      int dd[4] = {d[w].x, d[w].y, d[w].z, d[w].w};
#pragma unroll
      for (int q = 0; q < 4; q++) {
        int b = dd[q] >> 7;
        int slot = base[b] + rk[w * 4 + q];
        if (slot < BCAP)
          bedge[(size_t)b * BCAP + slot] =
              (unsigned)ss[q] | ((unsigned)(dd[q] & 127) << 17);
      }
    }
  }
}

// ---- bucket-count exclusive scan (one block) -> bbase, off[NN] -------------
__global__ __launch_bounds__(1024) void k_bscan(const int* __restrict__ bcur,
                                                int* __restrict__ bbase,
                                                int* __restrict__ off) {
  __shared__ int sh[1024];
  int t = threadIdx.x;
  int v = (t < NBK) ? min(bcur[t], BCAP) : 0;
  sh[t] = v;
  __syncthreads();
  for (int d = 1; d < 1024; d <<= 1) {
    int a = (t >= d) ? sh[t - d] : 0;
    __syncthreads();
    sh[t] += a;
    __syncthreads();
  }
  if (t < NBK) bbase[t] = sh[t] - v;  // exclusive
  if (t == 1023) off[NN] = sh[1023];  // total (== kept edges)
}

// ---- per-bucket: hist -> node offsets (off) -> CSR fill --------------------
__global__ __launch_bounds__(256) void k_bfill2(const int* __restrict__ bcur,
                                                const int* __restrict__ bbase,
                                                const unsigned* __restrict__ bedge,
                                                int* __restrict__ off,
                                                int* __restrict__ csr) {
  __shared__ int h[128];
  __shared__ int sc[128];
  __shared__ int curs[128];
  const int b = blockIdx.x;
  const int t = threadIdx.x;
  if (t < 128) h[t] = 0;
  __syncthreads();
  const int cnt = min(bcur[b], BCAP);
  const unsigned* be = bedge + (size_t)b * BCAP;
  for (int i = t; i < cnt; i += 256) atomicAdd(&h[(be[i] >> 17) & 127], 1);
  __syncthreads();
  int v = (t < 128) ? h[t] : 0;
  if (t < 128) sc[t] = v;
  __syncthreads();
  for (int d = 1; d < 128; d <<= 1) {
    int a = (t >= d && t < 128) ? sc[t - d] : 0;
    __syncthreads();
    if (t < 128) sc[t] += a;
    __syncthreads();
  }
  if (t < 128) {
    int o = bbase[b] + sc[t] - v;  // exclusive node offset
    int n = b * 128 + t;
    if (n < NN) off[n] = o;
    curs[t] = o;
  }
  __syncthreads();
  for (int i = t; i < cnt; i += 256) {
    unsigned u = be[i];
    int node = (u >> 17) & 127;
    int p = atomicAdd(&curs[node], 1);
    csr[p] = (int)(u & 0x1FFFF);
  }
}

// ---- pos prepack: [N][3] fp32 -> padded float4 (1 load/neighbor in layer1) -
__global__ __launch_bounds__(256) void k_pospack(const float* __restrict__ pos,
                                                 float4* __restrict__ pos4) {
  int n = blockIdx.x * 256 + threadIdx.x;
  if (n >= NN) return;
  pos4[n] = make_float4(pos[n * 3], pos[n * 3 + 1], pos[n * 3 + 2], 0.f);
}

// ------- weight pack: fp32 [k][n] -> fp16 in MFMA B-fragment order ----------
struct WPtrs { const float* w[9]; };
__global__ __launch_bounds__(256) void k_packw(WPtrs wp, f16* __restrict__ out) {
  int t = blockIdx.x * 256 + threadIdx.x;  // 9 * 16384
  int mat = t >> 14;
  int idx = t & 16383;
  int j = idx & 7;
  int lane = (idx >> 3) & 63;
  int ks = (idx >> 9) & 3;
  int nt = idx >> 11;
  int c16 = lane & 15, quad = lane >> 4;
  int k = ks * 32 + quad * 8 + j;
  int n = nt * 16 + c16;
  out[(size_t)mat * 16384 + idx] = (f16)wp.w[mat][k * CC + n];
}

// ---- FUSED layer 1: agg3 (thread-per-node, LDS) + node update (3 -> 128) ---
__global__ __launch_bounds__(256) void k_layer1(
    const int* __restrict__ off, const int* __restrict__ csr,
    const float4* __restrict__ pos4, const float* __restrict__ wl,
    const float* __restrict__ bl, const float* __restrict__ wr,
    const float* __restrict__ g, const float* __restrict__ be,
    const float* __restrict__ bm, const float* __restrict__ bv,
    f16* __restrict__ x) {
  __shared__ float sa[256][3];
  const int t = threadIdx.x;
  const int nbase = blockIdx.x * 256;
  {
    const int n = nbase + t;
    float a0 = 0.f, a1 = 0.f, a2 = 0.f;
    if (n < NN) {
      const int b = off[n], e = off[n + 1];
      int i = b;
      for (; i + 4 <= e; i += 4) {
        float4 p0 = pos4[csr[i]];
        float4 p1 = pos4[csr[i + 1]];
        float4 p2 = pos4[csr[i + 2]];
        float4 p3 = pos4[csr[i + 3]];
        a0 += (p0.x + p1.x) + (p2.x + p3.x);
        a1 += (p0.y + p1.y) + (p2.y + p3.y);
        a2 += (p0.z + p1.z) + (p2.z + p3.z);
      }
      for (; i < e; i++) {
        float4 p = pos4[csr[i]];
        a0 += p.x;
        a1 += p.y;
        a2 += p.z;
      }
      const float rd = 1.0f / fmaxf((float)(e - b), 1.0f);
      a0 *= rd;
      a1 *= rd;
      a2 *= rd;
    }
    sa[t][0] = a0;
    sa[t][1] = a1;
    sa[t][2] = a2;
  }
  __syncthreads();
  const int c = t & 127;
  const int np = t >> 7;  // node parity (uniform per wave)
  const float Wl0 = wl[c], Wl1 = wl[CC + c], Wl2 = wl[2 * CC + c];
  const float Wr0 = wr[c], Wr1 = wr[CC + c], Wr2 = wr[2 * CC + c];
  const float sc = g[c] * rsqrtf(bv[c] + 1e-5f);
  const float o0 = be[c] + (bl[c] - bm[c]) * sc;
  const int nend = min(nbase + 256, NN);
#pragma unroll 4
  for (int n = nbase + np; n < nend; n += 2) {
    const int ln = n - nbase;
    float4 p = pos4[n];
    float acc = sa[ln][0] * Wl0 + sa[ln][1] * Wl1 + sa[ln][2] * Wl2 +
                p.x * Wr0 + p.y * Wr1 + p.z * Wr2;
    x[(size_t)n * CC + c] = (f16)fmaxf(acc * sc + o0, 0.0f);
  }
}

// -------- aggregate (C=128): one wave per node, fma_mix accumulate ----------
// 16-deep main loop + 8-deep unpredicated + 8-deep clamped tail. All branch
// conditions are wave-uniform (lim is per-node).
__global__ __launch_bounds__(256) void k_aggregate(const int* __restrict__ off,
                                                   const int* __restrict__ csr,
                                                   const f16* __restrict__ x,
                                                   f16* __restrict__ agg) {
  const int n = blockIdx.x * 4 + (threadIdx.x >> 6);
  const int lane = threadIdx.x & 63;
  const int b = off[n], e = off[n + 1];
  float a0 = 0.f, a1 = 0.f;
  int i = b;
  // clean 16-deep blocks
  for (; i + 16 <= e; i += 16) {
    int sdx[16];
#pragma unroll
    for (int q = 0; q < 16; q++) sdx[q] = csr[i + q];
    f16x2 v[16];
#pragma unroll
    for (int q = 0; q < 16; q++)
      v[q] = *(const f16x2*)(x + (size_t)sdx[q] * CC + lane * 2);
#pragma unroll
    for (int q = 0; q < 16; q++) ACC_MIX(a0, a1, v[q]);
  }
  // one unpredicated 8-block if at least 8 remain
  if (i + 8 <= e) {
    int sdx[8];
#pragma unroll
    for (int q = 0; q < 8; q++) sdx[q] = csr[i + q];
    f16x2 v[8];
#pragma unroll
    for (int q = 0; q < 8; q++)
      v[q] = *(const f16x2*)(x + (size_t)sdx[q] * CC + lane * 2);
#pragma unroll
    for (int q = 0; q < 8; q++) ACC_MIX(a0, a1, v[q]);
    i += 8;
  }
  // clamped predicated 8-tail (dup loads = same-addr L1 hits; uniform preds)
  const int lim = e - i;  // 0..7
  if (lim > 0) {
    int sdx[8];
#pragma unroll
    for (int q = 0; q < 8; q++) sdx[q] = csr[i + (q < lim ? q : lim - 1)];
    f16x2 v[8];
#pragma unroll
    for (int q = 0; q < 8; q++)
      v[q] = *(const f16x2*)(x + (size_t)sdx[q] * CC + lane * 2);
#pragma unroll
    for (int q = 0; q < 8; q++) {
      if (q < lim) ACC_MIX(a0, a1, v[q]);
    }
  }
  const float rd = 1.0f / fmaxf((float)(e - b), 1.0f);
  f16x2 o;
  o[0] = (f16)(a0 * rd);
  o[1] = (f16)(a1 * rd);
  *(f16x2*)(agg + (size_t)n * CC + lane * 2) = o;
}

// ---- SAGE MFMA fp16 (128-row / 512-thread blocks): D = agg@wl + x@wr -------
__global__ __launch_bounds__(512) void k_sage_mfma(
    const f16* __restrict__ xin, f16* __restrict__ xout,
    const f16* __restrict__ agg, const f16* __restrict__ wl,
    const f16* __restrict__ wr, const float* __restrict__ bl,
    const float* __restrict__ g, const float* __restrict__ be,
    const float* __restrict__ bm, const float* __restrict__ bv) {
  const int lane = threadIdx.x & 63;
  const int wave = threadIdx.x >> 6;  // 0..7
  const int c16 = lane & 15;
  const int quad = lane >> 4;
  const int n0 = blockIdx.x * 128 + wave * 16;
  const int rowX = min(n0 + c16, NP - 1);  // last block can overshoot NP
  const int rowA = min(rowX, NN - 1);      // agg (in d_out) has NN rows
  const f16* px = xin + (size_t)rowX * CC + quad * 8;
  const f16* pa = agg + (size_t)rowA * CC + quad * 8;
  f32x4 acc[8];
#pragma unroll
  for (int t = 0; t < 8; t++) acc[t] = {0.f, 0.f, 0.f, 0.f};
#pragma unroll
  for (int ks = 0; ks < 4; ks++) {
    f16x8 Ax = *(const f16x8*)(px + ks * 32);
    f16x8 Aa = *(const f16x8*)(pa + ks * 32);
#pragma unroll
    for (int nt = 0; nt < 8; nt++) {
      const size_t wo = (size_t)((nt * 4 + ks) * 64 + lane) * 8;
      f16x8 Bl = *(const f16x8*)(wl + wo);
      f16x8 Br = *(const f16x8*)(wr + wo);
      acc[nt] = MFMA16(Aa, Bl, acc[nt]);
      acc[nt] = MFMA16(Ax, Br, acc[nt]);
    }
  }
#pragma unroll
  for (int nt = 0; nt < 8; nt++) {
    const int col = nt * 16 + c16;
    const float blc = bl[col];
    const float sc = g[col] * rsqrtf(bv[col] + 1e-5f);
    const float mm = bm[col];
    const float bb = be[col];
#pragma unroll
    for (int r = 0; r < 4; r++) {
      const int node = n0 + quad * 4 + r;
      if (node < NN) {
        float yv = fmaxf((acc[nt][r] + blc - mm) * sc + bb, 0.0f);
        xout[(size_t)node * CC + col] = (f16)yv;
      }
    }
  }
}

// -------- fused FC head (128-row / 512-thread): 3 chained GEMMs -------------
__global__ __launch_bounds__(512) void k_dense_fused(
    const f16* __restrict__ x, const f16* __restrict__ w1,
    const f16* __restrict__ w2, const f16* __restrict__ w3,
    const float* __restrict__ b1, const float* __restrict__ b2,
    const float* __restrict__ b3, float* __restrict__ out) {
  const int lane = threadIdx.x & 63;
  const int wave = threadIdx.x >> 6;  // 0..7
  const int c16 = lane & 15;
  const int quad = lane >> 4;
  const int n0 = blockIdx.x * 128 + wave * 16;
  const int lrow = wave * 16;
  __shared__ f16 sh[128][136];  // +8 pad

  f32x4 acc[8];
#pragma unroll
  for (int t = 0; t < 8; t++) acc[t] = {0.f, 0.f, 0.f, 0.f};
  const int rowX = min(n0 + c16, NP - 1);
  const f16* px = x + (size_t)rowX * CC + quad * 8;
#pragma unroll
  for (int ks = 0; ks < 4; ks++) {
    f16x8 Ax = *(const f16x8*)(px + ks * 32);
#pragma unroll
    for (int nt = 0; nt < 8; nt++) {
      f16x8 B = *(const f16x8*)(w1 + (size_t)((nt * 4 + ks) * 64 + lane) * 8);
      acc[nt] = MFMA16(Ax, B, acc[nt]);
    }
  }
#pragma unroll
  for (int nt = 0; nt < 8; nt++) {
    const int col = nt * 16 + c16;
    const float bc = b1[col];
#pragma unroll
    for (int r = 0; r < 4; r++)
      sh[lrow + quad * 4 + r][col] = (f16)fmaxf(acc[nt][r] + bc, 0.0f);
  }
  // FC2 (wave-local rows, no barrier needed)
#pragma unroll
  for (int t = 0; t < 8; t++) acc[t] = {0.f, 0.f, 0.f, 0.f};
#pragma unroll
  for (int ks = 0; ks < 4; ks++) {
    f16x8 Ax = *(const f16x8*)&sh[lrow + c16][ks * 32 + quad * 8];
#pragma unroll
    for (int nt = 0; nt < 8; nt++) {
      f16x8 B = *(const f16x8*)(w2 + (size_t)((nt * 4 + ks) * 64 + lane) * 8);
      acc[nt] = MFMA16(Ax, B, acc[nt]);
    }
  }
#pragma unroll
  for (int nt = 0; nt < 8; nt++) {
    const int col = nt * 16 + c16;
    const float bc = b2[col];
#pragma unroll
    for (int r = 0; r < 4; r++)
      sh[lrow + quad * 4 + r][col] = (f16)(acc[nt][r] + bc);
  }
  // FC3 -> out (fp32)
#pragma unroll
  for (int t = 0; t < 8; t++) acc[t] = {0.f, 0.f, 0.f, 0.f};
#pragma unroll
  for (int ks = 0; ks < 4; ks++) {
    f16x8 Ax = *(const f16x8*)&sh[lrow + c16][ks * 32 + quad * 8];
#pragma unroll
    for (int nt = 0; nt < 8; nt++) {
      f16x8 B = *(const f16x8*)(w3 + (size_t)((nt * 4 + ks) * 64 + lane) * 8);
      acc[nt] = MFMA16(Ax, B, acc[nt]);
    }
  }
#pragma unroll
  for (int nt = 0; nt < 8; nt++) {
    const int col = nt * 16 + c16;
    const float bc = b3[col];
#pragma unroll
    for (int r = 0; r < 4; r++) {
      const int node = n0 + quad * 4 + r;
      if (node < NN) out[(size_t)node * CC + col] = acc[nt][r] + bc;
    }
  }
}

extern "C" void kernel_launch(void* const* d_in, const int* in_sizes, int n_in,
                              void* d_out, int out_size, void* d_ws,
                              size_t ws_size, hipStream_t stream) {
  const float* pos = (const float*)d_in[0];
  const int* ei = (const int*)d_in[1];
  const int* src = ei;
  const int* dst = ei + EE;
  auto P = [&](int i) { return (const float*)d_in[i]; };

  // ws: bcur[NBK] | bbase[NBK] | off[NN+4 pad] | bedge[NBK*BCAP] | csr[E] |
  //     wp16 | xa | xb   (~62.5 MB). bedge is dead after k_bfill2 -> reused
  //     for pos4[NN]. LAYOUT INVARIANT: off+NN+4 makes bedge/csr/wp16/xa/xb
  //     all 256B-aligned (misalignment cost 33% extra FETCH through R9).
  int* bcur = (int*)d_ws;
  int* bbase = bcur + NBK;
  int* off = bbase + NBK;
  unsigned* bedge = (unsigned*)(off + NN + 4);  // 256B-aligned
  int* csr = (int*)(bedge + (size_t)NBK * BCAP);
  f16* wp16 = (f16*)(csr + EE);
  f16* xa = wp16 + 9 * 16384;
  f16* xb = xa + (size_t)NP * CC;

  float4* pos4 = (float4*)bedge;  // reuse (dead after k_bfill2)

  f16* agg = (f16*)d_out;  // scratch until the final dense overwrites d_out

  hipMemsetAsync(bcur, 0, NBK * sizeof(int), stream);

  // CSR build: partition -> bucket scan -> per-bucket offsets+fill
  k_part<<<(EE / 4 + 4095) / 4096, 1024, 0, stream>>>(src, dst, bcur, bedge);
  k_bscan<<<1, 1024, 0, stream>>>(bcur, bbase, off);
  k_bfill2<<<NBK, 256, 0, stream>>>(bcur, bbase, bedge, off, csr);

  // pos prepack (into the now-dead bedge region)
  k_pospack<<<(NN + 255) / 256, 256, 0, stream>>>(pos, pos4);

  WPtrs wp;
  const int wsrc[9] = {9, 11, 16, 18, 23, 25, 30, 32, 34};
  for (int i = 0; i < 9; i++) wp.w[i] = P(wsrc[i]);
  k_packw<<<(9 * 16384) / 256, 256, 0, stream>>>(wp, wp16);

  // layer 1 (Cin=3), fused aggregate + node update
  k_layer1<<<(NN + 255) / 256, 256, 0, stream>>>(
      off, csr, pos4, P(2), P(3), P(4), P(5), P(6), P(7), P(8), xa);

  // layers 2..4: ping-pong xa -> xb -> xa -> xb
  const f16* xi = xa;
  f16* xo = xb;
  for (int l = 1; l < 4; l++) {
    int base = 2 + 7 * l;
    int mat = (l - 1) * 2;
    k_aggregate<<<NN / 4, 256, 0, stream>>>(off, csr, xi, agg);
    k_sage_mfma<<<NBS, 512, 0, stream>>>(xi, xo, agg,
                                         wp16 + (size_t)mat * 16384,
                                         wp16 + (size_t)(mat + 1) * 16384,
                                         P(base + 1), P(base + 3), P(base + 4),
                                         P(base + 5), P(base + 6));
    const f16* t = xi;
    xi = xo;
    xo = (f16*)t;
  }

  // fused FC head
  k_dense_fused<<<NBS, 512, 0, stream>>>(xi, wp16 + (size_t)6 * 16384,
                                         wp16 + (size_t)7 * 16384,
                                         wp16 + (size_t)8 * 16384, P(31), P(33),
                                         P(35), (float*)d_out);
}

// Round 12
// 514.639 us; speedup vs baseline: 1.0167x; 1.0167x over previous
//
#include <hip/hip_runtime.h>

#define NN 100000
#define EE 1600000
#define CC 128
#define NP 100032   // padded to 64-row tiles (1563 * 64)
#define NBK 782     // dst buckets of 128 nodes (782*128 = 100096 >= NN)
#define BCAP 2304   // bucket capacity: E/NBK=2046 expected, +5.6 sigma slack
#define NBS 782     // 128-row MFMA tiles (782*128 = 100096 >= NP)

typedef _Float16 f16;
typedef __attribute__((ext_vector_type(2))) f16 f16x2;
typedef __attribute__((ext_vector_type(8))) f16 f16x8;
typedef __attribute__((ext_vector_type(4))) float f32x4;

#define MFMA16(a, b, c) __builtin_amdgcn_mfma_f32_16x16x32_f16(a, b, c, 0, 0, 0)

// LEDGER (R1-R11): flat [row][128ch] + wave-per-node 16-deep gather is the
// aggregate optimum (58.2 us). R10: 256B-aligning xa/xb cut FETCH 257->178 MB
// (rows straddled 3 lines when 8B-misaligned). R11: fma_mix cut VALUBusy
// 80->47% with ZERO duration change -> aggregate is memory-path-bound at
// ~3.5 TB/s; VALU is slack; kernel frozen in R10 form. Failed challengers:
// 16ch slabs (R2), LDS atomics (R3 50x), quad/node (R4), degree-sort atomics
// (R5), oct+partials (R6), NT hints (R7), sub-hist CSR (R7), agg+sage gather
// fusion (R8 occupancy 70->33%). This round: fuse layer-4 sage into the
// dense head (MFMA+MFMA, wave-local LDS relay; kills 51 MB round trip).
// LAYOUT INVARIANT: keep all ws buffers 256B-aligned (off+NN+4 does this).

// ---- phase 1: partition edges into dst-buckets; rank saved from 1st pass ----
__global__ __launch_bounds__(1024) void k_part(const int* __restrict__ src,
                                               const int* __restrict__ dst,
                                               int* __restrict__ bcur,
                                               unsigned* __restrict__ bedge) {
  __shared__ int hist[NBK];
  __shared__ int base[NBK];
  const int t = threadIdx.x;
  for (int i = t; i < NBK; i += 1024) hist[i] = 0;
  __syncthreads();
  const int4* src4 = (const int4*)src;
  const int4* dst4 = (const int4*)dst;
  int4 s[4], d[4];
  int rk[16];
  bool val[4];
#pragma unroll
  for (int w = 0; w < 4; w++) {
    int i4 = blockIdx.x * 4096 + w * 1024 + t;
    val[w] = (i4 < EE / 4);
    if (val[w]) {
      s[w] = src4[i4];
      d[w] = dst4[i4];
      rk[w * 4 + 0] = atomicAdd(&hist[d[w].x >> 7], 1);
      rk[w * 4 + 1] = atomicAdd(&hist[d[w].y >> 7], 1);
      rk[w * 4 + 2] = atomicAdd(&hist[d[w].z >> 7], 1);
      rk[w * 4 + 3] = atomicAdd(&hist[d[w].w >> 7], 1);
    }
  }
  __syncthreads();
  for (int i = t; i < NBK; i += 1024) {
    int c = hist[i];
    base[i] = c ? atomicAdd(&bcur[i], c) : 0;
  }
  __syncthreads();
#pragma unroll
  for (int w = 0; w < 4; w++) {
    if (val[w]) {
      int ss[4] = {s[w].x, s[w].y, s[w].z, s[w].w};
      int dd[4] = {d[w].x, d[w].y, d[w].z, d[w].w};
#pragma unroll
      for (int q = 0; q < 4; q++) {
        int b = dd[q] >> 7;
        int slot = base[b] + rk[w * 4 + q];
        if (slot < BCAP)
          bedge[(size_t)b * BCAP + slot] =
              (unsigned)ss[q] | ((unsigned)(dd[q] & 127) << 17);
      }
    }
  }
}

// ---- bucket-count exclusive scan (one block) -> bbase, off[NN] -------------
__global__ __launch_bounds__(1024) void k_bscan(const int* __restrict__ bcur,
                                                int* __restrict__ bbase,
                                                int* __restrict__ off) {
  __shared__ int sh[1024];
  int t = threadIdx.x;
  int v = (t < NBK) ? min(bcur[t], BCAP) : 0;
  sh[t] = v;
  __syncthreads();
  for (int d = 1; d < 1024; d <<= 1) {
    int a = (t >= d) ? sh[t - d] : 0;
    __syncthreads();
    sh[t] += a;
    __syncthreads();
  }
  if (t < NBK) bbase[t] = sh[t] - v;  // exclusive
  if (t == 1023) off[NN] = sh[1023];  // total (== kept edges)
}

// ---- per-bucket: hist -> node offsets (off) -> CSR fill --------------------
__global__ __launch_bounds__(256) void k_bfill2(const int* __restrict__ bcur,
                                                const int* __restrict__ bbase,
                                                const unsigned* __restrict__ bedge,
                                                int* __restrict__ off,
                                                int* __restrict__ csr) {
  __shared__ int h[128];
  __shared__ int sc[128];
  __shared__ int curs[128];
  const int b = blockIdx.x;
  const int t = threadIdx.x;
  if (t < 128) h[t] = 0;
  __syncthreads();
  const int cnt = min(bcur[b], BCAP);
  const unsigned* be = bedge + (size_t)b * BCAP;
  for (int i = t; i < cnt; i += 256) atomicAdd(&h[(be[i] >> 17) & 127], 1);
  __syncthreads();
  int v = (t < 128) ? h[t] : 0;
  if (t < 128) sc[t] = v;
  __syncthreads();
  for (int d = 1; d < 128; d <<= 1) {
    int a = (t >= d && t < 128) ? sc[t - d] : 0;
    __syncthreads();
    if (t < 128) sc[t] += a;
    __syncthreads();
  }
  if (t < 128) {
    int o = bbase[b] + sc[t] - v;  // exclusive node offset
    int n = b * 128 + t;
    if (n < NN) off[n] = o;
    curs[t] = o;
  }
  __syncthreads();
  for (int i = t; i < cnt; i += 256) {
    unsigned u = be[i];
    int node = (u >> 17) & 127;
    int p = atomicAdd(&curs[node], 1);
    csr[p] = (int)(u & 0x1FFFF);
  }
}

// ---- pos prepack: [N][3] fp32 -> padded float4 (1 load/neighbor in layer1) -
__global__ __launch_bounds__(256) void k_pospack(const float* __restrict__ pos,
                                                 float4* __restrict__ pos4) {
  int n = blockIdx.x * 256 + threadIdx.x;
  if (n >= NN) return;
  pos4[n] = make_float4(pos[n * 3], pos[n * 3 + 1], pos[n * 3 + 2], 0.f);
}

// ------- weight pack: fp32 [k][n] -> fp16 in MFMA B-fragment order ----------
struct WPtrs { const float* w[9]; };
__global__ __launch_bounds__(256) void k_packw(WPtrs wp, f16* __restrict__ out) {
  int t = blockIdx.x * 256 + threadIdx.x;  // 9 * 16384
  int mat = t >> 14;
  int idx = t & 16383;
  int j = idx & 7;
  int lane = (idx >> 3) & 63;
  int ks = (idx >> 9) & 3;
  int nt = idx >> 11;
  int c16 = lane & 15, quad = lane >> 4;
  int k = ks * 32 + quad * 8 + j;
  int n = nt * 16 + c16;
  out[(size_t)mat * 16384 + idx] = (f16)wp.w[mat][k * CC + n];
}

// ---- FUSED layer 1: agg3 (thread-per-node, LDS) + node update (3 -> 128) ---
__global__ __launch_bounds__(256) void k_layer1(
    const int* __restrict__ off, const int* __restrict__ csr,
    const float4* __restrict__ pos4, const float* __restrict__ wl,
    const float* __restrict__ bl, const float* __restrict__ wr,
    const float* __restrict__ g, const float* __restrict__ be,
    const float* __restrict__ bm, const float* __restrict__ bv,
    f16* __restrict__ x) {
  __shared__ float sa[256][3];
  const int t = threadIdx.x;
  const int nbase = blockIdx.x * 256;
  {
    const int n = nbase + t;
    float a0 = 0.f, a1 = 0.f, a2 = 0.f;
    if (n < NN) {
      const int b = off[n], e = off[n + 1];
      int i = b;
      for (; i + 4 <= e; i += 4) {
        float4 p0 = pos4[csr[i]];
        float4 p1 = pos4[csr[i + 1]];
        float4 p2 = pos4[csr[i + 2]];
        float4 p3 = pos4[csr[i + 3]];
        a0 += (p0.x + p1.x) + (p2.x + p3.x);
        a1 += (p0.y + p1.y) + (p2.y + p3.y);
        a2 += (p0.z + p1.z) + (p2.z + p3.z);
      }
      for (; i < e; i++) {
        float4 p = pos4[csr[i]];
        a0 += p.x;
        a1 += p.y;
        a2 += p.z;
      }
      const float rd = 1.0f / fmaxf((float)(e - b), 1.0f);
      a0 *= rd;
      a1 *= rd;
      a2 *= rd;
    }
    sa[t][0] = a0;
    sa[t][1] = a1;
    sa[t][2] = a2;
  }
  __syncthreads();
  const int c = t & 127;
  const int np = t >> 7;  // node parity (uniform per wave)
  const float Wl0 = wl[c], Wl1 = wl[CC + c], Wl2 = wl[2 * CC + c];
  const float Wr0 = wr[c], Wr1 = wr[CC + c], Wr2 = wr[2 * CC + c];
  const float sc = g[c] * rsqrtf(bv[c] + 1e-5f);
  const float o0 = be[c] + (bl[c] - bm[c]) * sc;
  const int nend = min(nbase + 256, NN);
#pragma unroll 4
  for (int n = nbase + np; n < nend; n += 2) {
    const int ln = n - nbase;
    float4 p = pos4[n];
    float acc = sa[ln][0] * Wl0 + sa[ln][1] * Wl1 + sa[ln][2] * Wl2 +
                p.x * Wr0 + p.y * Wr1 + p.z * Wr2;
    x[(size_t)n * CC + c] = (f16)fmaxf(acc * sc + o0, 0.0f);
  }
}

// -------- aggregate (C=128): one wave per node, 16-deep load pipeline -------
// Frozen R10 form: memory-path-bound at ~3.5 TB/s (R11 proved VALU slack).
__global__ __launch_bounds__(256) void k_aggregate(const int* __restrict__ off,
                                                   const int* __restrict__ csr,
                                                   const f16* __restrict__ x,
                                                   f16* __restrict__ agg) {
  const int n = blockIdx.x * 4 + (threadIdx.x >> 6);
  const int lane = threadIdx.x & 63;
  const int b = off[n], e = off[n + 1];
  float a0 = 0.f, a1 = 0.f;
  int i = b;
  // clean 16-deep blocks
  for (; i + 16 <= e; i += 16) {
    int sdx[16];
#pragma unroll
    for (int q = 0; q < 16; q++) sdx[q] = csr[i + q];
    f16x2 v[16];
#pragma unroll
    for (int q = 0; q < 16; q++)
      v[q] = *(const f16x2*)(x + (size_t)sdx[q] * CC + lane * 2);
#pragma unroll
    for (int q = 0; q < 16; q++) {
      a0 += (float)v[q][0];
      a1 += (float)v[q][1];
    }
  }
  // one predicated 16-block tail: clamp index (dup loads = same-addr L1 hits)
  const int lim = e - i;
  if (lim > 0) {
    int sdx[16];
#pragma unroll
    for (int q = 0; q < 16; q++) sdx[q] = csr[i + (q < lim ? q : lim - 1)];
    f16x2 v[16];
#pragma unroll
    for (int q = 0; q < 16; q++)
      v[q] = *(const f16x2*)(x + (size_t)sdx[q] * CC + lane * 2);
#pragma unroll
    for (int q = 0; q < 16; q++) {
      if (q < lim) {
        a0 += (float)v[q][0];
        a1 += (float)v[q][1];
      }
    }
  }
  const float rd = 1.0f / fmaxf((float)(e - b), 1.0f);
  f16x2 o;
  o[0] = (f16)(a0 * rd);
  o[1] = (f16)(a1 * rd);
  *(f16x2*)(agg + (size_t)n * CC + lane * 2) = o;
}

// ---- SAGE MFMA fp16 (128-row / 512-thread blocks): D = agg@wl + x@wr -------
__global__ __launch_bounds__(512) void k_sage_mfma(
    const f16* __restrict__ xin, f16* __restrict__ xout,
    const f16* __restrict__ agg, const f16* __restrict__ wl,
    const f16* __restrict__ wr, const float* __restrict__ bl,
    const float* __restrict__ g, const float* __restrict__ be,
    const float* __restrict__ bm, const float* __restrict__ bv) {
  const int lane = threadIdx.x & 63;
  const int wave = threadIdx.x >> 6;  // 0..7
  const int c16 = lane & 15;
  const int quad = lane >> 4;
  const int n0 = blockIdx.x * 128 + wave * 16;
  const int rowX = min(n0 + c16, NP - 1);  // last block can overshoot NP
  const int rowA = min(rowX, NN - 1);      // agg (in d_out) has NN rows
  const f16* px = xin + (size_t)rowX * CC + quad * 8;
  const f16* pa = agg + (size_t)rowA * CC + quad * 8;
  f32x4 acc[8];
#pragma unroll
  for (int t = 0; t < 8; t++) acc[t] = {0.f, 0.f, 0.f, 0.f};
#pragma unroll
  for (int ks = 0; ks < 4; ks++) {
    f16x8 Ax = *(const f16x8*)(px + ks * 32);
    f16x8 Aa = *(const f16x8*)(pa + ks * 32);
#pragma unroll
    for (int nt = 0; nt < 8; nt++) {
      const size_t wo = (size_t)((nt * 4 + ks) * 64 + lane) * 8;
      f16x8 Bl = *(const f16x8*)(wl + wo);
      f16x8 Br = *(const f16x8*)(wr + wo);
      acc[nt] = MFMA16(Aa, Bl, acc[nt]);
      acc[nt] = MFMA16(Ax, Br, acc[nt]);
    }
  }
#pragma unroll
  for (int nt = 0; nt < 8; nt++) {
    const int col = nt * 16 + c16;
    const float blc = bl[col];
    const float sc = g[col] * rsqrtf(bv[col] + 1e-5f);
    const float mm = bm[col];
    const float bb = be[col];
#pragma unroll
    for (int r = 0; r < 4; r++) {
      const int node = n0 + quad * 4 + r;
      if (node < NN) {
        float yv = fmaxf((acc[nt][r] + blc - mm) * sc + bb, 0.0f);
        xout[(size_t)node * CC + col] = (f16)yv;
      }
    }
  }
}

// ---- FUSED layer-4 SAGE + FC head (128-row / 512-thread, wave-local) -------
// Phase 0: sage4 acc = agg@wl + x@wr, BN+ReLU -> f16 into the LDS tile
// (same rounding point as the old global store -> numerics identical).
// Phases 1-3: dense FC1/FC2/FC3 exactly as before, FC1 reading LDS.
// All row sets are wave-local -> zero barriers. Kills the 51 MB relay.
__global__ __launch_bounds__(512) void k_sage_dense(
    const f16* __restrict__ xin, const f16* __restrict__ agg,
    const f16* __restrict__ wl, const f16* __restrict__ wr,
    const float* __restrict__ bl, const float* __restrict__ g,
    const float* __restrict__ be, const float* __restrict__ bm,
    const float* __restrict__ bv, const f16* __restrict__ w1,
    const f16* __restrict__ w2, const f16* __restrict__ w3,
    const float* __restrict__ b1, const float* __restrict__ b2,
    const float* __restrict__ b3, float* __restrict__ out) {
  const int lane = threadIdx.x & 63;
  const int wave = threadIdx.x >> 6;  // 0..7
  const int c16 = lane & 15;
  const int quad = lane >> 4;
  const int n0 = blockIdx.x * 128 + wave * 16;
  const int lrow = wave * 16;
  __shared__ f16 sh[128][136];  // +8 pad

  f32x4 acc[8];
  // ---- phase 0: sage4 ----
#pragma unroll
  for (int t = 0; t < 8; t++) acc[t] = {0.f, 0.f, 0.f, 0.f};
  {
    const int rowX = min(n0 + c16, NP - 1);
    const int rowA = min(rowX, NN - 1);  // agg (in xb) has NN valid rows
    const f16* px = xin + (size_t)rowX * CC + quad * 8;
    const f16* pa = agg + (size_t)rowA * CC + quad * 8;
#pragma unroll
    for (int ks = 0; ks < 4; ks++) {
      f16x8 Ax = *(const f16x8*)(px + ks * 32);
      f16x8 Aa = *(const f16x8*)(pa + ks * 32);
#pragma unroll
      for (int nt = 0; nt < 8; nt++) {
        const size_t wo = (size_t)((nt * 4 + ks) * 64 + lane) * 8;
        f16x8 Bl = *(const f16x8*)(wl + wo);
        f16x8 Br = *(const f16x8*)(wr + wo);
        acc[nt] = MFMA16(Aa, Bl, acc[nt]);
        acc[nt] = MFMA16(Ax, Br, acc[nt]);
      }
    }
  }
#pragma unroll
  for (int nt = 0; nt < 8; nt++) {
    const int col = nt * 16 + c16;
    const float blc = bl[col];
    const float sc = g[col] * rsqrtf(bv[col] + 1e-5f);
    const float mm = bm[col];
    const float bb = be[col];
#pragma unroll
    for (int r = 0; r < 4; r++) {
      float yv = fmaxf((acc[nt][r] + blc - mm) * sc + bb, 0.0f);
      sh[lrow + quad * 4 + r][col] = (f16)yv;  // wave-local rows
    }
  }
  // ---- phase 1: FC1 (A from LDS) ----
#pragma unroll
  for (int t = 0; t < 8; t++) acc[t] = {0.f, 0.f, 0.f, 0.f};
#pragma unroll
  for (int ks = 0; ks < 4; ks++) {
    f16x8 Ax = *(const f16x8*)&sh[lrow + c16][ks * 32 + quad * 8];
#pragma unroll
    for (int nt = 0; nt < 8; nt++) {
      f16x8 B = *(const f16x8*)(w1 + (size_t)((nt * 4 + ks) * 64 + lane) * 8);
      acc[nt] = MFMA16(Ax, B, acc[nt]);
    }
  }
#pragma unroll
  for (int nt = 0; nt < 8; nt++) {
    const int col = nt * 16 + c16;
    const float bc = b1[col];
#pragma unroll
    for (int r = 0; r < 4; r++)
      sh[lrow + quad * 4 + r][col] = (f16)fmaxf(acc[nt][r] + bc, 0.0f);
  }
  // ---- phase 2: FC2 ----
#pragma unroll
  for (int t = 0; t < 8; t++) acc[t] = {0.f, 0.f, 0.f, 0.f};
#pragma unroll
  for (int ks = 0; ks < 4; ks++) {
    f16x8 Ax = *(const f16x8*)&sh[lrow + c16][ks * 32 + quad * 8];
#pragma unroll
    for (int nt = 0; nt < 8; nt++) {
      f16x8 B = *(const f16x8*)(w2 + (size_t)((nt * 4 + ks) * 64 + lane) * 8);
      acc[nt] = MFMA16(Ax, B, acc[nt]);
    }
  }
#pragma unroll
  for (int nt = 0; nt < 8; nt++) {
    const int col = nt * 16 + c16;
    const float bc = b2[col];
#pragma unroll
    for (int r = 0; r < 4; r++)
      sh[lrow + quad * 4 + r][col] = (f16)(acc[nt][r] + bc);
  }
  // ---- phase 3: FC3 -> out (fp32) ----
#pragma unroll
  for (int t = 0; t < 8; t++) acc[t] = {0.f, 0.f, 0.f, 0.f};
#pragma unroll
  for (int ks = 0; ks < 4; ks++) {
    f16x8 Ax = *(const f16x8*)&sh[lrow + c16][ks * 32 + quad * 8];
#pragma unroll
    for (int nt = 0; nt < 8; nt++) {
      f16x8 B = *(const f16x8*)(w3 + (size_t)((nt * 4 + ks) * 64 + lane) * 8);
      acc[nt] = MFMA16(Ax, B, acc[nt]);
    }
  }
#pragma unroll
  for (int nt = 0; nt < 8; nt++) {
    const int col = nt * 16 + c16;
    const float bc = b3[col];
#pragma unroll
    for (int r = 0; r < 4; r++) {
      const int node = n0 + quad * 4 + r;
      if (node < NN) out[(size_t)node * CC + col] = acc[nt][r] + bc;
    }
  }
}

extern "C" void kernel_launch(void* const* d_in, const int* in_sizes, int n_in,
                              void* d_out, int out_size, void* d_ws,
                              size_t ws_size, hipStream_t stream) {
  const float* pos = (const float*)d_in[0];
  const int* ei = (const int*)d_in[1];
  const int* src = ei;
  const int* dst = ei + EE;
  auto P = [&](int i) { return (const float*)d_in[i]; };

  // ws: bcur[NBK] | bbase[NBK] | off[NN+4 pad] | bedge[NBK*BCAP] | csr[E] |
  //     wp16 | xa | xb   (~62.5 MB). bedge is dead after k_bfill2 -> reused
  //     for pos4[NN]. LAYOUT INVARIANT: off+NN+4 makes bedge/csr/wp16/xa/xb
  //     all 256B-aligned (misalignment cost 33% extra FETCH through R9).
  int* bcur = (int*)d_ws;
  int* bbase = bcur + NBK;
  int* off = bbase + NBK;
  unsigned* bedge = (unsigned*)(off + NN + 4);  // 256B-aligned
  int* csr = (int*)(bedge + (size_t)NBK * BCAP);
  f16* wp16 = (f16*)(csr + EE);
  f16* xa = wp16 + 9 * 16384;
  f16* xb = xa + (size_t)NP * CC;

  float4* pos4 = (float4*)bedge;  // reuse (dead after k_bfill2)

  f16* agg = (f16*)d_out;  // scratch for layers 2-3 (dense overwrites later)

  hipMemsetAsync(bcur, 0, NBK * sizeof(int), stream);

  // CSR build: partition -> bucket scan -> per-bucket offsets+fill
  k_part<<<(EE / 4 + 4095) / 4096, 1024, 0, stream>>>(src, dst, bcur, bedge);
  k_bscan<<<1, 1024, 0, stream>>>(bcur, bbase, off);
  k_bfill2<<<NBK, 256, 0, stream>>>(bcur, bbase, bedge, off, csr);

  // pos prepack (into the now-dead bedge region)
  k_pospack<<<(NN + 255) / 256, 256, 0, stream>>>(pos, pos4);

  WPtrs wp;
  const int wsrc[9] = {9, 11, 16, 18, 23, 25, 30, 32, 34};
  for (int i = 0; i < 9; i++) wp.w[i] = P(wsrc[i]);
  k_packw<<<(9 * 16384) / 256, 256, 0, stream>>>(wp, wp16);

  // layer 1 (Cin=3), fused aggregate + node update
  k_layer1<<<(NN + 255) / 256, 256, 0, stream>>>(
      off, csr, pos4, P(2), P(3), P(4), P(5), P(6), P(7), P(8), xa);

  // layers 2..3: ping-pong xa -> xb -> xa (agg scratch in d_out)
  const f16* xi = xa;
  f16* xo = xb;
  for (int l = 1; l < 3; l++) {
    int base = 2 + 7 * l;
    int mat = (l - 1) * 2;
    k_aggregate<<<NN / 4, 256, 0, stream>>>(off, csr, xi, agg);
    k_sage_mfma<<<NBS, 512, 0, stream>>>(xi, xo, agg,
                                         wp16 + (size_t)mat * 16384,
                                         wp16 + (size_t)(mat + 1) * 16384,
                                         P(base + 1), P(base + 3), P(base + 4),
                                         P(base + 5), P(base + 6));
    const f16* t = xi;
    xi = xo;
    xo = (f16*)t;
  }
  // after l=1,2: xi == xa (layer-3 activations), xb free.

  // layer 4 fused with FC head: aggregate into xb (NOT d_out -- the fused
  // kernel writes fp32 out to d_out, which would alias an agg there).
  k_aggregate<<<NN / 4, 256, 0, stream>>>(off, csr, xi, xb);
  k_sage_dense<<<NBS, 512, 0, stream>>>(
      xi, xb, wp16 + (size_t)4 * 16384, wp16 + (size_t)5 * 16384,
      P(24), P(26), P(27), P(28), P(29),
      wp16 + (size_t)6 * 16384, wp16 + (size_t)7 * 16384,
      wp16 + (size_t)8 * 16384, P(31), P(33), P(35), (float*)d_out);
}

// Round 13
// 488.291 us; speedup vs baseline: 1.0716x; 1.0540x over previous
//
#include <hip/hip_runtime.h>

#define NN 100000
#define EE 1600000
#define CC 128
#define NP 100032   // padded to 64-row tiles (1563 * 64)
#define NBK 782     // dst buckets of 128 nodes (782*128 = 100096 >= NN)
#define BCAP 2304   // bucket capacity: E/NBK=2046 expected, +5.6 sigma slack
#define NB 1563     // 64-row MFMA tiles (1563*64 = NP exactly)

typedef _Float16 f16;
typedef __attribute__((ext_vector_type(2))) f16 f16x2;
typedef __attribute__((ext_vector_type(8))) f16 f16x8;
typedef __attribute__((ext_vector_type(4))) float f32x4;

#define MFMA16(a, b, c) __builtin_amdgcn_mfma_f32_16x16x32_f16(a, b, c, 0, 0, 0)

// LEDGER (R1-R12): flat [row][128ch] + wave-per-node 16-deep gather is the
// aggregate optimum (58.2 us, frozen; R11 proved memory-path-bound, VALU
// slack). R10: 256B-aligning xa/xb cut FETCH 257->178 MB. R12: layer4-sage
// + FC-head fusion kept (514.6 us); its counters showed MfmaUtil 7%/VALU 8%/
// occ 32% -> latency-bound from 128-row/512-thread blocks (34KB LDS, ~3
// blocks/CU). R10's 128-row switch was confounded with the alignment fix;
// weight-refetch saving it targeted is ~1.5us of L2 traffic. This round:
// revert MFMA kernels to 64-row/256-thread (17KB LDS, ~6-8 blocks/CU).
// Failed challengers: 16ch slabs (R2), LDS atomics (R3 50x), quad/node
// (R4), degree-sort atomics (R5), oct+partials (R6), NT hints (R7),
// sub-hist CSR (R7), gather+MFMA fusion (R8), fma_mix (R11 neutral).
// LAYOUT INVARIANT: keep all ws buffers 256B-aligned (off+NN+4 does this).

// ---- phase 1: partition edges into dst-buckets; rank saved from 1st pass ----
__global__ __launch_bounds__(1024) void k_part(const int* __restrict__ src,
                                               const int* __restrict__ dst,
                                               int* __restrict__ bcur,
                                               unsigned* __restrict__ bedge) {
  __shared__ int hist[NBK];
  __shared__ int base[NBK];
  const int t = threadIdx.x;
  for (int i = t; i < NBK; i += 1024) hist[i] = 0;
  __syncthreads();
  const int4* src4 = (const int4*)src;
  const int4* dst4 = (const int4*)dst;
  int4 s[4], d[4];
  int rk[16];
  bool val[4];
#pragma unroll
  for (int w = 0; w < 4; w++) {
    int i4 = blockIdx.x * 4096 + w * 1024 + t;
    val[w] = (i4 < EE / 4);
    if (val[w]) {
      s[w] = src4[i4];
      d[w] = dst4[i4];
      rk[w * 4 + 0] = atomicAdd(&hist[d[w].x >> 7], 1);
      rk[w * 4 + 1] = atomicAdd(&hist[d[w].y >> 7], 1);
      rk[w * 4 + 2] = atomicAdd(&hist[d[w].z >> 7], 1);
      rk[w * 4 + 3] = atomicAdd(&hist[d[w].w >> 7], 1);
    }
  }
  __syncthreads();
  for (int i = t; i < NBK; i += 1024) {
    int c = hist[i];
    base[i] = c ? atomicAdd(&bcur[i], c) : 0;
  }
  __syncthreads();
#pragma unroll
  for (int w = 0; w < 4; w++) {
    if (val[w]) {
      int ss[4] = {s[w].x, s[w].y, s[w].z, s[w].w};
      int dd[4] = {d[w].x, d[w].y, d[w].z, d[w].w};
#pragma unroll
      for (int q = 0; q < 4; q++) {
        int b = dd[q] >> 7;
        int slot = base[b] + rk[w * 4 + q];
        if (slot < BCAP)
          bedge[(size_t)b * BCAP + slot] =
              (unsigned)ss[q] | ((unsigned)(dd[q] & 127) << 17);
      }
    }
  }
}

// ---- bucket-count exclusive scan (one block) -> bbase, off[NN] -------------
__global__ __launch_bounds__(1024) void k_bscan(const int* __restrict__ bcur,
                                                int* __restrict__ bbase,
                                                int* __restrict__ off) {
  __shared__ int sh[1024];
  int t = threadIdx.x;
  int v = (t < NBK) ? min(bcur[t], BCAP) : 0;
  sh[t] = v;
  __syncthreads();
  for (int d = 1; d < 1024; d <<= 1) {
    int a = (t >= d) ? sh[t - d] : 0;
    __syncthreads();
    sh[t] += a;
    __syncthreads();
  }
  if (t < NBK) bbase[t] = sh[t] - v;  // exclusive
  if (t == 1023) off[NN] = sh[1023];  // total (== kept edges)
}

// ---- per-bucket: hist -> node offsets (off) -> CSR fill --------------------
__global__ __launch_bounds__(256) void k_bfill2(const int* __restrict__ bcur,
                                                const int* __restrict__ bbase,
                                                const unsigned* __restrict__ bedge,
                                                int* __restrict__ off,
                                                int* __restrict__ csr) {
  __shared__ int h[128];
  __shared__ int sc[128];
  __shared__ int curs[128];
  const int b = blockIdx.x;
  const int t = threadIdx.x;
  if (t < 128) h[t] = 0;
  __syncthreads();
  const int cnt = min(bcur[b], BCAP);
  const unsigned* be = bedge + (size_t)b * BCAP;
  for (int i = t; i < cnt; i += 256) atomicAdd(&h[(be[i] >> 17) & 127], 1);
  __syncthreads();
  int v = (t < 128) ? h[t] : 0;
  if (t < 128) sc[t] = v;
  __syncthreads();
  for (int d = 1; d < 128; d <<= 1) {
    int a = (t >= d && t < 128) ? sc[t - d] : 0;
    __syncthreads();
    if (t < 128) sc[t] += a;
    __syncthreads();
  }
  if (t < 128) {
    int o = bbase[b] + sc[t] - v;  // exclusive node offset
    int n = b * 128 + t;
    if (n < NN) off[n] = o;
    curs[t] = o;
  }
  __syncthreads();
  for (int i = t; i < cnt; i += 256) {
    unsigned u = be[i];
    int node = (u >> 17) & 127;
    int p = atomicAdd(&curs[node], 1);
    csr[p] = (int)(u & 0x1FFFF);
  }
}

// ---- pos prepack: [N][3] fp32 -> padded float4 (1 load/neighbor in layer1) -
__global__ __launch_bounds__(256) void k_pospack(const float* __restrict__ pos,
                                                 float4* __restrict__ pos4) {
  int n = blockIdx.x * 256 + threadIdx.x;
  if (n >= NN) return;
  pos4[n] = make_float4(pos[n * 3], pos[n * 3 + 1], pos[n * 3 + 2], 0.f);
}

// ------- weight pack: fp32 [k][n] -> fp16 in MFMA B-fragment order ----------
struct WPtrs { const float* w[9]; };
__global__ __launch_bounds__(256) void k_packw(WPtrs wp, f16* __restrict__ out) {
  int t = blockIdx.x * 256 + threadIdx.x;  // 9 * 16384
  int mat = t >> 14;
  int idx = t & 16383;
  int j = idx & 7;
  int lane = (idx >> 3) & 63;
  int ks = (idx >> 9) & 3;
  int nt = idx >> 11;
  int c16 = lane & 15, quad = lane >> 4;
  int k = ks * 32 + quad * 8 + j;
  int n = nt * 16 + c16;
  out[(size_t)mat * 16384 + idx] = (f16)wp.w[mat][k * CC + n];
}

// ---- FUSED layer 1: agg3 (thread-per-node, LDS) + node update (3 -> 128) ---
__global__ __launch_bounds__(256) void k_layer1(
    const int* __restrict__ off, const int* __restrict__ csr,
    const float4* __restrict__ pos4, const float* __restrict__ wl,
    const float* __restrict__ bl, const float* __restrict__ wr,
    const float* __restrict__ g, const float* __restrict__ be,
    const float* __restrict__ bm, const float* __restrict__ bv,
    f16* __restrict__ x) {
  __shared__ float sa[256][3];
  const int t = threadIdx.x;
  const int nbase = blockIdx.x * 256;
  {
    const int n = nbase + t;
    float a0 = 0.f, a1 = 0.f, a2 = 0.f;
    if (n < NN) {
      const int b = off[n], e = off[n + 1];
      int i = b;
      for (; i + 4 <= e; i += 4) {
        float4 p0 = pos4[csr[i]];
        float4 p1 = pos4[csr[i + 1]];
        float4 p2 = pos4[csr[i + 2]];
        float4 p3 = pos4[csr[i + 3]];
        a0 += (p0.x + p1.x) + (p2.x + p3.x);
        a1 += (p0.y + p1.y) + (p2.y + p3.y);
        a2 += (p0.z + p1.z) + (p2.z + p3.z);
      }
      for (; i < e; i++) {
        float4 p = pos4[csr[i]];
        a0 += p.x;
        a1 += p.y;
        a2 += p.z;
      }
      const float rd = 1.0f / fmaxf((float)(e - b), 1.0f);
      a0 *= rd;
      a1 *= rd;
      a2 *= rd;
    }
    sa[t][0] = a0;
    sa[t][1] = a1;
    sa[t][2] = a2;
  }
  __syncthreads();
  const int c = t & 127;
  const int np = t >> 7;  // node parity (uniform per wave)
  const float Wl0 = wl[c], Wl1 = wl[CC + c], Wl2 = wl[2 * CC + c];
  const float Wr0 = wr[c], Wr1 = wr[CC + c], Wr2 = wr[2 * CC + c];
  const float sc = g[c] * rsqrtf(bv[c] + 1e-5f);
  const float o0 = be[c] + (bl[c] - bm[c]) * sc;
  const int nend = min(nbase + 256, NN);
#pragma unroll 4
  for (int n = nbase + np; n < nend; n += 2) {
    const int ln = n - nbase;
    float4 p = pos4[n];
    float acc = sa[ln][0] * Wl0 + sa[ln][1] * Wl1 + sa[ln][2] * Wl2 +
                p.x * Wr0 + p.y * Wr1 + p.z * Wr2;
    x[(size_t)n * CC + c] = (f16)fmaxf(acc * sc + o0, 0.0f);
  }
}

// -------- aggregate (C=128): one wave per node, 16-deep load pipeline -------
// Frozen R10 form: memory-path-bound at ~3.5 TB/s (R11 proved VALU slack).
__global__ __launch_bounds__(256) void k_aggregate(const int* __restrict__ off,
                                                   const int* __restrict__ csr,
                                                   const f16* __restrict__ x,
                                                   f16* __restrict__ agg) {
  const int n = blockIdx.x * 4 + (threadIdx.x >> 6);
  const int lane = threadIdx.x & 63;
  const int b = off[n], e = off[n + 1];
  float a0 = 0.f, a1 = 0.f;
  int i = b;
  // clean 16-deep blocks
  for (; i + 16 <= e; i += 16) {
    int sdx[16];
#pragma unroll
    for (int q = 0; q < 16; q++) sdx[q] = csr[i + q];
    f16x2 v[16];
#pragma unroll
    for (int q = 0; q < 16; q++)
      v[q] = *(const f16x2*)(x + (size_t)sdx[q] * CC + lane * 2);
#pragma unroll
    for (int q = 0; q < 16; q++) {
      a0 += (float)v[q][0];
      a1 += (float)v[q][1];
    }
  }
  // one predicated 16-block tail: clamp index (dup loads = same-addr L1 hits)
  const int lim = e - i;
  if (lim > 0) {
    int sdx[16];
#pragma unroll
    for (int q = 0; q < 16; q++) sdx[q] = csr[i + (q < lim ? q : lim - 1)];
    f16x2 v[16];
#pragma unroll
    for (int q = 0; q < 16; q++)
      v[q] = *(const f16x2*)(x + (size_t)sdx[q] * CC + lane * 2);
#pragma unroll
    for (int q = 0; q < 16; q++) {
      if (q < lim) {
        a0 += (float)v[q][0];
        a1 += (float)v[q][1];
      }
    }
  }
  const float rd = 1.0f / fmaxf((float)(e - b), 1.0f);
  f16x2 o;
  o[0] = (f16)(a0 * rd);
  o[1] = (f16)(a1 * rd);
  *(f16x2*)(agg + (size_t)n * CC + lane * 2) = o;
}

// ---- SAGE MFMA fp16 (64-row / 256-thread blocks): D = agg@wl + x@wr --------
__global__ __launch_bounds__(256) void k_sage_mfma(
    const f16* __restrict__ xin, f16* __restrict__ xout,
    const f16* __restrict__ agg, const f16* __restrict__ wl,
    const f16* __restrict__ wr, const float* __restrict__ bl,
    const float* __restrict__ g, const float* __restrict__ be,
    const float* __restrict__ bm, const float* __restrict__ bv) {
  const int lane = threadIdx.x & 63;
  const int wave = threadIdx.x >> 6;  // 0..3
  const int c16 = lane & 15;
  const int quad = lane >> 4;
  const int n0 = blockIdx.x * 64 + wave * 16;
  const int rowX = n0 + c16;               // < NP (NB*64 == NP)
  const int rowA = min(rowX, NN - 1);      // agg (in d_out) has NN rows
  const f16* px = xin + (size_t)rowX * CC + quad * 8;
  const f16* pa = agg + (size_t)rowA * CC + quad * 8;
  f32x4 acc[8];
#pragma unroll
  for (int t = 0; t < 8; t++) acc[t] = {0.f, 0.f, 0.f, 0.f};
#pragma unroll
  for (int ks = 0; ks < 4; ks++) {
    f16x8 Ax = *(const f16x8*)(px + ks * 32);
    f16x8 Aa = *(const f16x8*)(pa + ks * 32);
#pragma unroll
    for (int nt = 0; nt < 8; nt++) {
      const size_t wo = (size_t)((nt * 4 + ks) * 64 + lane) * 8;
      f16x8 Bl = *(const f16x8*)(wl + wo);
      f16x8 Br = *(const f16x8*)(wr + wo);
      acc[nt] = MFMA16(Aa, Bl, acc[nt]);
      acc[nt] = MFMA16(Ax, Br, acc[nt]);
    }
  }
#pragma unroll
  for (int nt = 0; nt < 8; nt++) {
    const int col = nt * 16 + c16;
    const float blc = bl[col];
    const float sc = g[col] * rsqrtf(bv[col] + 1e-5f);
    const float mm = bm[col];
    const float bb = be[col];
#pragma unroll
    for (int r = 0; r < 4; r++) {
      const int node = n0 + quad * 4 + r;
      if (node < NN) {
        float yv = fmaxf((acc[nt][r] + blc - mm) * sc + bb, 0.0f);
        xout[(size_t)node * CC + col] = (f16)yv;
      }
    }
  }
}

// ---- FUSED layer-4 SAGE + FC head (64-row / 256-thread, wave-local) --------
// Phase 0: sage4 acc = agg@wl + x@wr, BN+ReLU -> f16 into the LDS tile.
// Phases 1-3: dense FC1/FC2/FC3, FC1 reading LDS. All rows wave-local ->
// zero barriers. 17KB LDS -> ~8 blocks/CU (R12's 34KB gave occ 32%).
__global__ __launch_bounds__(256) void k_sage_dense(
    const f16* __restrict__ xin, const f16* __restrict__ agg,
    const f16* __restrict__ wl, const f16* __restrict__ wr,
    const float* __restrict__ bl, const float* __restrict__ g,
    const float* __restrict__ be, const float* __restrict__ bm,
    const float* __restrict__ bv, const f16* __restrict__ w1,
    const f16* __restrict__ w2, const f16* __restrict__ w3,
    const float* __restrict__ b1, const float* __restrict__ b2,
    const float* __restrict__ b3, float* __restrict__ out) {
  const int lane = threadIdx.x & 63;
  const int wave = threadIdx.x >> 6;  // 0..3
  const int c16 = lane & 15;
  const int quad = lane >> 4;
  const int n0 = blockIdx.x * 64 + wave * 16;
  const int lrow = wave * 16;
  __shared__ f16 sh[64][136];  // +8 pad, 17408 B

  f32x4 acc[8];
  // ---- phase 0: sage4 ----
#pragma unroll
  for (int t = 0; t < 8; t++) acc[t] = {0.f, 0.f, 0.f, 0.f};
  {
    const int rowX = n0 + c16;           // < NP
    const int rowA = min(rowX, NN - 1);  // agg (in xb) has NN valid rows
    const f16* px = xin + (size_t)rowX * CC + quad * 8;
    const f16* pa = agg + (size_t)rowA * CC + quad * 8;
#pragma unroll
    for (int ks = 0; ks < 4; ks++) {
      f16x8 Ax = *(const f16x8*)(px + ks * 32);
      f16x8 Aa = *(const f16x8*)(pa + ks * 32);
#pragma unroll
      for (int nt = 0; nt < 8; nt++) {
        const size_t wo = (size_t)((nt * 4 + ks) * 64 + lane) * 8;
        f16x8 Bl = *(const f16x8*)(wl + wo);
        f16x8 Br = *(const f16x8*)(wr + wo);
        acc[nt] = MFMA16(Aa, Bl, acc[nt]);
        acc[nt] = MFMA16(Ax, Br, acc[nt]);
      }
    }
  }
#pragma unroll
  for (int nt = 0; nt < 8; nt++) {
    const int col = nt * 16 + c16;
    const float blc = bl[col];
    const float sc = g[col] * rsqrtf(bv[col] + 1e-5f);
    const float mm = bm[col];
    const float bb = be[col];
#pragma unroll
    for (int r = 0; r < 4; r++) {
      float yv = fmaxf((acc[nt][r] + blc - mm) * sc + bb, 0.0f);
      sh[lrow + quad * 4 + r][col] = (f16)yv;  // wave-local rows
    }
  }
  // ---- phase 1: FC1 (A from LDS) ----
#pragma unroll
  for (int t = 0; t < 8; t++) acc[t] = {0.f, 0.f, 0.f, 0.f};
#pragma unroll
  for (int ks = 0; ks < 4; ks++) {
    f16x8 Ax = *(const f16x8*)&sh[lrow + c16][ks * 32 + quad * 8];
#pragma unroll
    for (int nt = 0; nt < 8; nt++) {
      f16x8 B = *(const f16x8*)(w1 + (size_t)((nt * 4 + ks) * 64 + lane) * 8);
      acc[nt] = MFMA16(Ax, B, acc[nt]);
    }
  }
#pragma unroll
  for (int nt = 0; nt < 8; nt++) {
    const int col = nt * 16 + c16;
    const float bc = b1[col];
#pragma unroll
    for (int r = 0; r < 4; r++)
      sh[lrow + quad * 4 + r][col] = (f16)fmaxf(acc[nt][r] + bc, 0.0f);
  }
  // ---- phase 2: FC2 ----
#pragma unroll
  for (int t = 0; t < 8; t++) acc[t] = {0.f, 0.f, 0.f, 0.f};
#pragma unroll
  for (int ks = 0; ks < 4; ks++) {
    f16x8 Ax = *(const f16x8*)&sh[lrow + c16][ks * 32 + quad * 8];
#pragma unroll
    for (int nt = 0; nt < 8; nt++) {
      f16x8 B = *(const f16x8*)(w2 + (size_t)((nt * 4 + ks) * 64 + lane) * 8);
      acc[nt] = MFMA16(Ax, B, acc[nt]);
    }
  }
#pragma unroll
  for (int nt = 0; nt < 8; nt++) {
    const int col = nt * 16 + c16;
    const float bc = b2[col];
#pragma unroll
    for (int r = 0; r < 4; r++)
      sh[lrow + quad * 4 + r][col] = (f16)(acc[nt][r] + bc);
  }
  // ---- phase 3: FC3 -> out (fp32) ----
#pragma unroll
  for (int t = 0; t < 8; t++) acc[t] = {0.f, 0.f, 0.f, 0.f};
#pragma unroll
  for (int ks = 0; ks < 4; ks++) {
    f16x8 Ax = *(const f16x8*)&sh[lrow + c16][ks * 32 + quad * 8];
#pragma unroll
    for (int nt = 0; nt < 8; nt++) {
      f16x8 B = *(const f16x8*)(w3 + (size_t)((nt * 4 + ks) * 64 + lane) * 8);
      acc[nt] = MFMA16(Ax, B, acc[nt]);
    }
  }
#pragma unroll
  for (int nt = 0; nt < 8; nt++) {
    const int col = nt * 16 + c16;
    const float bc = b3[col];
#pragma unroll
    for (int r = 0; r < 4; r++) {
      const int node = n0 + quad * 4 + r;
      if (node < NN) out[(size_t)node * CC + col] = acc[nt][r] + bc;
    }
  }
}

extern "C" void kernel_launch(void* const* d_in, const int* in_sizes, int n_in,
                              void* d_out, int out_size, void* d_ws,
                              size_t ws_size, hipStream_t stream) {
  const float* pos = (const float*)d_in[0];
  const int* ei = (const int*)d_in[1];
  const int* src = ei;
  const int* dst = ei + EE;
  auto P = [&](int i) { return (const float*)d_in[i]; };

  // ws: bcur[NBK] | bbase[NBK] | off[NN+4 pad] | bedge[NBK*BCAP] | csr[E] |
  //     wp16 | xa | xb   (~62.5 MB). bedge is dead after k_bfill2 -> reused
  //     for pos4[NN]. LAYOUT INVARIANT: off+NN+4 makes bedge/csr/wp16/xa/xb
  //     all 256B-aligned (misalignment cost 33% extra FETCH through R9).
  int* bcur = (int*)d_ws;
  int* bbase = bcur + NBK;
  int* off = bbase + NBK;
  unsigned* bedge = (unsigned*)(off + NN + 4);  // 256B-aligned
  int* csr = (int*)(bedge + (size_t)NBK * BCAP);
  f16* wp16 = (f16*)(csr + EE);
  f16* xa = wp16 + 9 * 16384;
  f16* xb = xa + (size_t)NP * CC;

  float4* pos4 = (float4*)bedge;  // reuse (dead after k_bfill2)

  f16* agg = (f16*)d_out;  // scratch for layers 2-3 (dense overwrites later)

  hipMemsetAsync(bcur, 0, NBK * sizeof(int), stream);

  // CSR build: partition -> bucket scan -> per-bucket offsets+fill
  k_part<<<(EE / 4 + 4095) / 4096, 1024, 0, stream>>>(src, dst, bcur, bedge);
  k_bscan<<<1, 1024, 0, stream>>>(bcur, bbase, off);
  k_bfill2<<<NBK, 256, 0, stream>>>(bcur, bbase, bedge, off, csr);

  // pos prepack (into the now-dead bedge region)
  k_pospack<<<(NN + 255) / 256, 256, 0, stream>>>(pos, pos4);

  WPtrs wp;
  const int wsrc[9] = {9, 11, 16, 18, 23, 25, 30, 32, 34};
  for (int i = 0; i < 9; i++) wp.w[i] = P(wsrc[i]);
  k_packw<<<(9 * 16384) / 256, 256, 0, stream>>>(wp, wp16);

  // layer 1 (Cin=3), fused aggregate + node update
  k_layer1<<<(NN + 255) / 256, 256, 0, stream>>>(
      off, csr, pos4, P(2), P(3), P(4), P(5), P(6), P(7), P(8), xa);

  // layers 2..3: ping-pong xa -> xb -> xa (agg scratch in d_out)
  const f16* xi = xa;
  f16* xo = xb;
  for (int l = 1; l < 3; l++) {
    int base = 2 + 7 * l;
    int mat = (l - 1) * 2;
    k_aggregate<<<NN / 4, 256, 0, stream>>>(off, csr, xi, agg);
    k_sage_mfma<<<NB, 256, 0, stream>>>(xi, xo, agg,
                                        wp16 + (size_t)mat * 16384,
                                        wp16 + (size_t)(mat + 1) * 16384,
                                        P(base + 1), P(base + 3), P(base + 4),
                                        P(base + 5), P(base + 6));
    const f16* t = xi;
    xi = xo;
    xo = (f16*)t;
  }
  // after l=1,2: xi == xa (layer-3 activations), xb free.

  // layer 4 fused with FC head: aggregate into xb (NOT d_out -- the fused
  // kernel writes fp32 out to d_out, which would alias an agg there).
  k_aggregate<<<NN / 4, 256, 0, stream>>>(off, csr, xi, xb);
  k_sage_dense<<<NB, 256, 0, stream>>>(
      xi, xb, wp16 + (size_t)4 * 16384, wp16 + (size_t)5 * 16384,
      P(24), P(26), P(27), P(28), P(29),
      wp16 + (size_t)6 * 16384, wp16 + (size_t)7 * 16384,
      wp16 + (size_t)8 * 16384, P(31), P(33), P(35), (float*)d_out);
}